// Round 1
// baseline (748.652 us; speedup 1.0000x reference)
//
#include <hip/hip_runtime.h>
#include <stdint.h>

// ---------------------------------------------------------------------------
// QRNNCell: out = g*(Ux X Ux^H) + (1-g)*(Uh H Uh^H)  (complex, per batch)
// Per evolution: out = U * S^T where S = conj(U) * X^T.  Every GEMM is then
// A(M,K) x B^T(N,K) with K contiguous for both operands (m97 gemm_bt shape):
//   Stage 1: Y=[Sr;Si] (1024x512) = W1(1024x1024) x [xr|xi](512x1024 B^T)
//            W1 = [Ur Ui; -Ui Ur]
//   Stage 2: O=[Or;Oi] (1024x512) = W2(1024x2048) x [Sxr|Sxi|Shr|Shi]^T
//            W2 folds the sigmoid gate g/(1-g); epilogue writes fp32 d_out.
// bf16 MFMA 16x16x32, fp32 accumulate. 275 GFLOP total.
// ---------------------------------------------------------------------------

#define D_DIM 512
#define DD (D_DIM * D_DIM)
#define NBATCH 64

typedef __attribute__((ext_vector_type(8))) short short8;
typedef __attribute__((ext_vector_type(4))) float f32x4;

static __device__ __forceinline__ short f2bf(float f) {
  union { float f; unsigned int u; } v; v.f = f;
  unsigned int r = v.u + 0x7FFFu + ((v.u >> 16) & 1u);  // RNE
  return (short)(r >> 16);
}

static __device__ __forceinline__ void gload_lds16(const short* g, short* l) {
  __builtin_amdgcn_global_load_lds(
      (const __attribute__((address_space(1))) void*)g,
      (__attribute__((address_space(3))) void*)l, 16, 0, 0);
}

// ------------------------- K0: build W1 (2x1Mi) + W2 (2Mi) ------------------
__global__ void build_w(const float* __restrict__ Uxr, const float* __restrict__ Uxi,
                        const float* __restrict__ Uhr, const float* __restrict__ Uhi,
                        const float* __restrict__ Lam,
                        short* __restrict__ W1, short* __restrict__ W2) {
  const float g  = 1.0f / (1.0f + expf(-Lam[0]));
  const float gh = 1.0f - g;
  const int total = 2 * 1024 * 1024 + 1024 * 2048;
  for (int i = blockIdx.x * blockDim.x + threadIdx.x; i < total;
       i += gridDim.x * blockDim.x) {
    if (i < 2 * 1024 * 1024) {
      const int ev = i >> 20;
      const int r  = (i >> 10) & 1023;
      const int c  = i & 1023;
      const float* Ur = ev ? Uhr : Uxr;
      const float* Ui = ev ? Uhi : Uxi;
      const int rr = r & 511, cc = c & 511;
      float v;
      if (r < 512) v = (c < 512) ?  Ur[rr * 512 + cc] : Ui[rr * 512 + cc];
      else         v = (c < 512) ? -Ui[rr * 512 + cc] : Ur[rr * 512 + cc];
      W1[i] = f2bf(v);
    } else {
      const int j   = i - 2 * 1024 * 1024;
      const int m   = j >> 11;      // 0..1023
      const int t   = j & 2047;
      const int seg = t >> 9;       // 0..3: Sxr,Sxi,Shr,Shi
      const int tq  = t & 511;
      const int row = m & 511;
      float v;
      if (m < 512) {  // Or rows
        switch (seg) {
          case 0:  v =  g  * Uxr[row * 512 + tq]; break;
          case 1:  v = -g  * Uxi[row * 512 + tq]; break;
          case 2:  v =  gh * Uhr[row * 512 + tq]; break;
          default: v = -gh * Uhi[row * 512 + tq]; break;
        }
      } else {        // Oi rows
        switch (seg) {
          case 0:  v =  g  * Uxi[row * 512 + tq]; break;
          case 1:  v =  g  * Uxr[row * 512 + tq]; break;
          case 2:  v =  gh * Uhi[row * 512 + tq]; break;
          default: v =  gh * Uhr[row * 512 + tq]; break;
        }
      }
      W2[j] = f2bf(v);
    }
  }
}

// --------------- K1: fp32 -> bf16 convert + [xr|xi] interleave --------------
// Bc layout: [cb][ev][512][1024]  (ev 0=x,1=h; cols 0..511 real, 512..1023 imag)
__global__ void convert_x(const float* __restrict__ xr, const float* __restrict__ xi,
                          const float* __restrict__ hr, const float* __restrict__ hi,
                          short* __restrict__ Bc, int b0, int cb) {
  const long total8 = (long)cb * 131072L;  // cb*2*512*1024/8
  const long stride = (long)gridDim.x * blockDim.x;
  for (long i = (long)blockIdx.x * blockDim.x + threadIdx.x; i < total8; i += stride) {
    const long o   = i << 3;
    const int  k   = (int)(o & 1023);
    const long rem = o >> 10;
    const int  t   = (int)(rem & 511);
    const long r2  = rem >> 9;
    const int  ev  = (int)(r2 & 1);
    const int  bl  = (int)(r2 >> 1);
    const float* src = ev ? ((k < 512) ? hr : hi) : ((k < 512) ? xr : xi);
    const float4* s = reinterpret_cast<const float4*>(
        src + (long)(b0 + bl) * DD + (long)t * 512 + (k & 511));
    const float4 v0 = s[0];
    const float4 v1 = s[1];
    short8 r;
    r[0] = f2bf(v0.x); r[1] = f2bf(v0.y); r[2] = f2bf(v0.z); r[3] = f2bf(v0.w);
    r[4] = f2bf(v1.x); r[5] = f2bf(v1.y); r[6] = f2bf(v1.z); r[7] = f2bf(v1.w);
    *reinterpret_cast<short8*>(Bc + o) = r;
  }
}

// ---------------- GEMM1: Y[1024x512] = W1[1024x1024] x Bc^T -----------------
__global__ __launch_bounds__(256) void gemm1(const short* __restrict__ W1,
                                             const short* __restrict__ Bc,
                                             short* __restrict__ Y) {
  const int mt = blockIdx.x >> 2;      // 0..7
  const int nt = blockIdx.x & 3;       // 0..3
  const int ev = blockIdx.y;
  const int bl = blockIdx.z;

  const short* A = W1 + ((long)ev << 20) + (long)mt * (128 * 1024);
  const short* B = Bc + ((long)(bl * 2 + ev) << 19) + (long)nt * (128 * 1024);
  short*       C = Y  + ((long)(bl * 2 + ev) << 19) + (long)mt * (128 * 512) + nt * 128;

  __shared__ __align__(16) short As[128 * 64];
  __shared__ __align__(16) short Bs[128 * 64];

  const int tid  = threadIdx.x;
  const int lane = tid & 63;
  const int w    = tid >> 6;
  const int wm   = (w >> 1) * 64;
  const int wn   = (w & 1) * 64;
  const int l15  = lane & 15;
  const int l4   = lane >> 4;
  const int srow = tid >> 3;           // 0..31
  const int sk   = (tid & 7) * 8;

  f32x4 acc[4][4];
#pragma unroll
  for (int i = 0; i < 4; ++i)
#pragma unroll
    for (int j = 0; j < 4; ++j)
#pragma unroll
      for (int r = 0; r < 4; ++r) acc[i][j][r] = 0.0f;

  for (int kt = 0; kt < 16; ++kt) {
    const short* Ag = A + (long)srow * 1024 + kt * 64 + sk;
    const short* Bg = B + (long)srow * 1024 + kt * 64 + sk;
#pragma unroll
    for (int i = 0; i < 4; ++i) {
      gload_lds16(Ag + (long)i * (32 * 1024), &As[(i * 256 + tid) * 8]);
      gload_lds16(Bg + (long)i * (32 * 1024), &Bs[(i * 256 + tid) * 8]);
    }
    __syncthreads();
#pragma unroll
    for (int kk = 0; kk < 64; kk += 32) {
      const int ko = kk + l4 * 8;
      short8 a[4], b[4];
#pragma unroll
      for (int i = 0; i < 4; ++i)
        a[i] = *reinterpret_cast<const short8*>(&As[(wm + i * 16 + l15) * 64 + ko]);
#pragma unroll
      for (int j = 0; j < 4; ++j)
        b[j] = *reinterpret_cast<const short8*>(&Bs[(wn + j * 16 + l15) * 64 + ko]);
#pragma unroll
      for (int i = 0; i < 4; ++i)
#pragma unroll
        for (int j = 0; j < 4; ++j)
          acc[i][j] = __builtin_amdgcn_mfma_f32_16x16x32_bf16(a[i], b[j], acc[i][j], 0, 0, 0);
    }
    __syncthreads();
  }

#pragma unroll
  for (int i = 0; i < 4; ++i)
#pragma unroll
    for (int j = 0; j < 4; ++j)
#pragma unroll
      for (int r = 0; r < 4; ++r) {
        const int m = wm + i * 16 + l4 * 4 + r;
        const int n = wn + j * 16 + l15;
        C[(long)m * 512 + n] = f2bf(acc[i][j][r]);
      }
}

// --------- GEMM2: O[1024x512] = W2[1024x2048] x Y-segments^T, -> fp32 -------
__global__ __launch_bounds__(256) void gemm2(const short* __restrict__ W2,
                                             const short* __restrict__ Y,
                                             float* __restrict__ out, int b0) {
  const int mt = blockIdx.x >> 2;      // 0..7  (<4: real rows, >=4: imag rows)
  const int nt = blockIdx.x & 3;       // 0..3
  const int bl = blockIdx.z;

  const short* A = W2 + (long)mt * (128 * 2048);

  __shared__ __align__(16) short As[128 * 64];
  __shared__ __align__(16) short Bs[128 * 64];

  const int tid  = threadIdx.x;
  const int lane = tid & 63;
  const int w    = tid >> 6;
  const int wm   = (w >> 1) * 64;
  const int wn   = (w & 1) * 64;
  const int l15  = lane & 15;
  const int l4   = lane >> 4;
  const int srow = tid >> 3;
  const int sk   = (tid & 7) * 8;

  f32x4 acc[4][4];
#pragma unroll
  for (int i = 0; i < 4; ++i)
#pragma unroll
    for (int j = 0; j < 4; ++j)
#pragma unroll
      for (int r = 0; r < 4; ++r) acc[i][j][r] = 0.0f;

  for (int kt = 0; kt < 32; ++kt) {
    const int seg  = kt >> 3;          // 0..3: Sxr,Sxi,Shr,Shi
    const int ev   = seg >> 1;
    const int half = seg & 1;
    const short* Ag = A + (long)srow * 2048 + kt * 64 + sk;
    const short* Bg = Y + ((long)(bl * 2 + ev) << 19)
                    + (long)(half * 512 + nt * 128 + srow) * 512 + (kt & 7) * 64 + sk;
#pragma unroll
    for (int i = 0; i < 4; ++i) {
      gload_lds16(Ag + (long)i * (32 * 2048), &As[(i * 256 + tid) * 8]);
      gload_lds16(Bg + (long)i * (32 * 512),  &Bs[(i * 256 + tid) * 8]);
    }
    __syncthreads();
#pragma unroll
    for (int kk = 0; kk < 64; kk += 32) {
      const int ko = kk + l4 * 8;
      short8 a[4], b[4];
#pragma unroll
      for (int i = 0; i < 4; ++i)
        a[i] = *reinterpret_cast<const short8*>(&As[(wm + i * 16 + l15) * 64 + ko]);
#pragma unroll
      for (int j = 0; j < 4; ++j)
        b[j] = *reinterpret_cast<const short8*>(&Bs[(wn + j * 16 + l15) * 64 + ko]);
#pragma unroll
      for (int i = 0; i < 4; ++i)
#pragma unroll
        for (int j = 0; j < 4; ++j)
          acc[i][j] = __builtin_amdgcn_mfma_f32_16x16x32_bf16(a[i], b[j], acc[i][j], 0, 0, 0);
    }
    __syncthreads();
  }

  const long obase = (mt >= 4 ? (long)NBATCH * DD : 0L)
                   + (long)(b0 + bl) * DD + (long)((mt & 3) * 128) * 512 + nt * 128;
#pragma unroll
  for (int i = 0; i < 4; ++i)
#pragma unroll
    for (int j = 0; j < 4; ++j)
#pragma unroll
      for (int r = 0; r < 4; ++r) {
        const int m = wm + i * 16 + l4 * 4 + r;
        const int n = wn + j * 16 + l15;
        out[obase + (long)m * 512 + n] = acc[i][j][r];
      }
}

// ---------------------------------------------------------------------------
extern "C" void kernel_launch(void* const* d_in, const int* in_sizes, int n_in,
                              void* d_out, int out_size, void* d_ws, size_t ws_size,
                              hipStream_t stream) {
  (void)in_sizes; (void)n_in; (void)out_size;
  const float* xr  = (const float*)d_in[0];
  const float* xi  = (const float*)d_in[1];
  const float* hr  = (const float*)d_in[2];
  const float* hi  = (const float*)d_in[3];
  const float* Uxr = (const float*)d_in[4];
  const float* Uxi = (const float*)d_in[5];
  const float* Uhr = (const float*)d_in[6];
  const float* Uhi = (const float*)d_in[7];
  const float* Lam = (const float*)d_in[8];
  float* out = (float*)d_out;
  char*  ws  = (char*)d_ws;

  // ws layout: W1 (4 MB) | W2 (4 MB) | Bc (chunk*2 MB) | Y (chunk*2 MB)
  short* W1 = (short*)ws;
  short* W2 = (short*)(ws + ((size_t)4 << 20));
  const size_t fixed = (size_t)8 << 20;
  const size_t perb  = (size_t)4 << 20;  // 2 MB Bc + 2 MB Y per batch
  int chunk = 1;
  if (ws_size > fixed + perb) {
    size_t c = (ws_size - fixed) / perb;
    chunk = (c > (size_t)NBATCH) ? NBATCH : (int)c;
  }
  short* Bc = (short*)(ws + fixed);
  short* Yw = (short*)(ws + fixed + (size_t)chunk * ((size_t)2 << 20));

  build_w<<<dim3(1024), dim3(256), 0, stream>>>(Uxr, Uxi, Uhr, Uhi, Lam, W1, W2);

  for (int b0 = 0; b0 < NBATCH; b0 += chunk) {
    const int cb = (NBATCH - b0 < chunk) ? (NBATCH - b0) : chunk;
    long total8 = (long)cb * 131072L;
    int cblocks = (int)((total8 + 255) / 256);
    if (cblocks > 2048) cblocks = 2048;
    convert_x<<<dim3(cblocks), dim3(256), 0, stream>>>(xr, xi, hr, hi, Bc, b0, cb);
    gemm1<<<dim3(32, 2, cb), dim3(256), 0, stream>>>(W1, Bc, Yw);
    gemm2<<<dim3(32, 1, cb), dim3(256), 0, stream>>>(W2, Yw, out, b0);
  }
}